// Round 6
// baseline (511.614 us; speedup 1.0000x reference)
//
#include <hip/hip_runtime.h>
#include <hip/hip_bf16.h>
#include <hip/hip_fp16.h>

// Problem dims (fixed)
#define B_  2
#define N_  1024
#define M_  2048
#define C_  1024
#define KV_ 768
#define H_  16
#define D_  64

typedef _Float16 half8 __attribute__((ext_vector_type(8)));
typedef float f32x4 __attribute__((ext_vector_type(4)));

// async global->LDS 16B; LDS dest must be wave-uniform base + lane*16.
__device__ inline void gload16(const _Float16* g, _Float16* l) {
    __builtin_amdgcn_global_load_lds(
        (const __attribute__((address_space(1))) unsigned int*)g,
        (__attribute__((address_space(3))) unsigned int*)l, 16, 0, 0);
}
__device__ inline void gload16f(const float* g, float* l) {
    __builtin_amdgcn_global_load_lds(
        (const __attribute__((address_space(1))) unsigned int*)g,
        (__attribute__((address_space(3))) unsigned int*)l, 16, 0, 0);
}

// ---------------------------------------------------------------------------
// All fp32->fp16 conversions in one grid-stride launch (full GPU).
// ---------------------------------------------------------------------------
#define NQ4  (B_ * N_ * C_ / 4)
#define NKV4 (B_ * M_ * KV_ / 4)
#define NWQ4 (C_ * C_ / 4)
#define NWK4 (2 * C_ * KV_ / 4)
#define NTOT4 (NQ4 + NKV4 + NWQ4 + NWK4 + NWQ4)

__global__ __launch_bounds__(256)
void cvt_all(const float* __restrict__ q, const float* __restrict__ kv,
             const float* __restrict__ Wq, const float* __restrict__ Wkv,
             const float* __restrict__ Wp,
             _Float16* __restrict__ qh, _Float16* __restrict__ kvh,
             _Float16* __restrict__ Wqh, _Float16* __restrict__ Wkvh,
             _Float16* __restrict__ Wph)
{
    int i = blockIdx.x * 256 + threadIdx.x;
    if (i >= NTOT4) return;
    const float* s; _Float16* d; int off; float sc = 1.0f;
    if (i < NQ4)                          { s = q;   d = qh;   off = i; sc = 0.125f; }
    else if (i < NQ4 + NKV4)              { s = kv;  d = kvh;  off = i - NQ4; }
    else if (i < NQ4 + NKV4 + NWQ4)       { s = Wq;  d = Wqh;  off = i - NQ4 - NKV4; }
    else if (i < NQ4 + NKV4 + NWQ4 + NWK4){ s = Wkv; d = Wkvh; off = i - NQ4 - NKV4 - NWQ4; }
    else                                  { s = Wp;  d = Wph;  off = i - NQ4 - NKV4 - NWQ4 - NWK4; }
    float4 v = ((const float4*)s)[off];
    union { _Float16 h[4]; unsigned long long u; } pk;
    pk.h[0] = (_Float16)(v.x * sc); pk.h[1] = (_Float16)(v.y * sc);
    pk.h[2] = (_Float16)(v.z * sc); pk.h[3] = (_Float16)(v.w * sc);
    ((unsigned long long*)d)[off] = pk.u;
}

// ---------------------------------------------------------------------------
// fp16 BT GEMM body: out[m,n] = sum_k A[m,k]*Bm[n,k]. 128x128, BK=32,
// global_load_lds(16B) + XOR k-seg swizzle. 4 waves (2x2 of 64x64).
// EPI 0: fp16 out0[m*ND+n];  EPI 1: split k_ws / v_ws(T).
// ---------------------------------------------------------------------------
template<int ND, int KD, int EPI>
__device__ __forceinline__
void gemm_body(const _Float16* A, const _Float16* Bm, void* out0, void* out1,
               _Float16* As, _Float16* Bs, int bx, int by)
{
    const int tid  = threadIdx.x;
    const int lane = tid & 63;
    const int w    = tid >> 6;
    const int l16  = lane & 15;
    const int quad = lane >> 4;
    const int wm   = w >> 1, wn = w & 1;
    const int m0   = by * 128;
    const int n0   = bx * 128;

    const int srow = tid >> 2;
    const int scol = ((tid & 3) ^ (srow & 3)) * 8;
    const int ldso = srow * 32 + (tid & 3) * 8;

    f32x4 acc[4][4];
    {
        f32x4 z = {0.f, 0.f, 0.f, 0.f};
        for (int i = 0; i < 4; i++) for (int j = 0; j < 4; j++) acc[i][j] = z;
    }

    for (int k0 = 0; k0 < KD; k0 += 32) {
        __syncthreads();
        gload16(A  + (size_t)(m0 + srow)      * KD + k0 + scol, As + ldso);
        gload16(A  + (size_t)(m0 + 64 + srow) * KD + k0 + scol, As + 64 * 32 + ldso);
        gload16(Bm + (size_t)(n0 + srow)      * KD + k0 + scol, Bs + ldso);
        gload16(Bm + (size_t)(n0 + 64 + srow) * KD + k0 + scol, Bs + 64 * 32 + ldso);
        __syncthreads();

        half8 af[4], bf[4];
        #pragma unroll
        for (int i = 0; i < 4; i++) {
            int r = wm * 64 + i * 16 + l16;
            af[i] = *(const half8*)&As[r * 32 + ((quad ^ (r & 3)) * 8)];
        }
        #pragma unroll
        for (int j = 0; j < 4; j++) {
            int r = wn * 64 + j * 16 + l16;
            bf[j] = *(const half8*)&Bs[r * 32 + ((quad ^ (r & 3)) * 8)];
        }
        #pragma unroll
        for (int i = 0; i < 4; i++)
            #pragma unroll
            for (int j = 0; j < 4; j++)
                acc[i][j] = __builtin_amdgcn_mfma_f32_16x16x32_f16(af[i], bf[j], acc[i][j], 0, 0, 0);
    }

    #pragma unroll
    for (int i = 0; i < 4; i++)
        #pragma unroll
        for (int j = 0; j < 4; j++) {
            int mb = m0 + wm * 64 + i * 16 + quad * 4;
            int n  = n0 + wn * 64 + j * 16 + l16;
            if (EPI == 0) {
                #pragma unroll
                for (int r = 0; r < 4; r++)
                    ((_Float16*)out0)[(size_t)(mb + r) * ND + n] = (_Float16)acc[i][j][r];
            } else {
                int b = mb >> 11, ml = mb & 2047;
                if (n < C_) {
                    int h = n >> 6, d = n & 63;
                    #pragma unroll
                    for (int r = 0; r < 4; r++)
                        ((_Float16*)out0)[((size_t)(b * H_ + h) * M_ + ml + r) * D_ + d] =
                            (_Float16)acc[i][j][r];
                } else {
                    int h = (n >> 6) & 15, d = n & 63;
                    union { _Float16 h4[4]; unsigned long long u; } pk;
                    #pragma unroll
                    for (int r = 0; r < 4; r++) pk.h4[r] = (_Float16)acc[i][j][r];
                    *(unsigned long long*)&((_Float16*)out1)[((size_t)(b * H_ + h) * D_ + d) * M_ + ml] = pk.u;
                }
            }
        }
}

// Merged Q-proj + KV-proj: blocks 0..127 = Qproj (8x16), 128..639 = KVproj (16x32).
__global__ __launch_bounds__(256)
void qkv_gemm(const _Float16* __restrict__ qh, const _Float16* __restrict__ Wqh,
              _Float16* __restrict__ qp,
              const _Float16* __restrict__ kvh, const _Float16* __restrict__ Wkvh,
              _Float16* __restrict__ k_ws, _Float16* __restrict__ v_ws)
{
    __shared__ _Float16 As[128 * 32];
    __shared__ _Float16 Bs[128 * 32];
    int id = blockIdx.x;
    if (id < 128)
        gemm_body<C_, C_, 0>(qh, Wqh, qp, nullptr, As, Bs, id & 7, id >> 3);
    else {
        int r = id - 128;
        gemm_body<2 * C_, KV_, 1>(kvh, Wkvh, k_ws, v_ws, As, Bs, r & 15, r >> 4);
    }
}

// ---------------------------------------------------------------------------
// Out projection: 64x64 tiles (512 blocks, 2/CU), BK=32, fp32 out + bias.
// ---------------------------------------------------------------------------
__global__ __launch_bounds__(256)
void outproj(const _Float16* __restrict__ A, const _Float16* __restrict__ Bm,
             float* __restrict__ out, const float* __restrict__ bias)
{
    __shared__ _Float16 As[64 * 32];
    __shared__ _Float16 Bs[64 * 32];

    const int tid  = threadIdx.x;
    const int lane = tid & 63;
    const int w    = tid >> 6;
    const int l16  = lane & 15;
    const int quad = lane >> 4;
    const int wm   = w >> 1, wn = w & 1;
    const int m0   = blockIdx.y * 64;
    const int n0   = blockIdx.x * 64;

    const int srow = tid >> 2;                       // 0..63
    const int scol = ((tid & 3) ^ (srow & 3)) * 8;
    const int ldso = srow * 32 + (tid & 3) * 8;

    f32x4 acc[2][2];
    {
        f32x4 z = {0.f, 0.f, 0.f, 0.f};
        for (int i = 0; i < 2; i++) for (int j = 0; j < 2; j++) acc[i][j] = z;
    }

    for (int k0 = 0; k0 < C_; k0 += 32) {
        __syncthreads();
        gload16(A  + (size_t)(m0 + srow) * C_ + k0 + scol, As + ldso);
        gload16(Bm + (size_t)(n0 + srow) * C_ + k0 + scol, Bs + ldso);
        __syncthreads();

        half8 af[2], bf[2];
        #pragma unroll
        for (int i = 0; i < 2; i++) {
            int r = wm * 32 + i * 16 + l16;
            af[i] = *(const half8*)&As[r * 32 + ((quad ^ (r & 3)) * 8)];
        }
        #pragma unroll
        for (int j = 0; j < 2; j++) {
            int r = wn * 32 + j * 16 + l16;
            bf[j] = *(const half8*)&Bs[r * 32 + ((quad ^ (r & 3)) * 8)];
        }
        #pragma unroll
        for (int i = 0; i < 2; i++)
            #pragma unroll
            for (int j = 0; j < 2; j++)
                acc[i][j] = __builtin_amdgcn_mfma_f32_16x16x32_f16(af[i], bf[j], acc[i][j], 0, 0, 0);
    }

    #pragma unroll
    for (int i = 0; i < 2; i++)
        #pragma unroll
        for (int j = 0; j < 2; j++)
            #pragma unroll
            for (int r = 0; r < 4; r++) {
                int m = m0 + wm * 32 + i * 16 + quad * 4 + r;
                int n = n0 + wn * 32 + j * 16 + l16;
                out[(size_t)m * C_ + n] = acc[i][j][r] + bias[n];
            }
}

// ---------------------------------------------------------------------------
// Flash attention v4: split-M across blocks for 2x occupancy.
// 1024 blocks = 32 bh x 16 n-tiles x 2 m-halves; 4 waves x 16 Q-rows each.
// LDS exactly 40960 B (Al dbuf 32K + Ps 8K) + VGPR<=128 (launch_bounds(256,4))
// -> 4 blocks/CU, all 1024 co-resident, 4 waves/SIMD (2x round-5).
// Each half accumulates unnormalized fp32 O-partial + row-sum partial into
// separate buffers (no atomics); `combine` sums+normalizes to fp16 x_ws.
// Alibi staged via global_load_lds DMA dbuf (v3 scheme, vmcnt-drain-safe);
// Ps compacted [4][16][64] with dword-XOR swizzle phys_dw = dw ^ (quad<<3)
// (roundtrip-verified; conflict-free writes).
// ---------------------------------------------------------------------------
__global__ __launch_bounds__(256, 4)
void flash_attn(const _Float16* __restrict__ qw, const _Float16* __restrict__ kw,
                const _Float16* __restrict__ vw, const float* __restrict__ alibi,
                const void* __restrict__ pmask,
                float* __restrict__ O0, float* __restrict__ O1,
                float* __restrict__ rs0, float* __restrict__ rs1)
{
    __shared__ _Float16 Ps[4][16][64];              // per-wave P tile, XOR-swizzled
    __shared__ __align__(16) float Al[2][64][64];   // alibi dbuf, seg-swizzled

    const int tid  = threadIdx.x;
    const int lane = tid & 63;
    const int w    = tid >> 6;
    const int l16  = lane & 15;
    const int quad = lane >> 4;

    // XCD-bijective remap: 1024 blocks, 128/XCD; each XCD owns 4 bh panels,
    // both m-halves of a (bh,n0) pair land on the same XCD (K/V L2-shared).
    const int bid  = blockIdx.x;
    const int xcd  = bid & 7;
    const int idx  = bid >> 3;            // 0..127
    const int bh   = xcd * 4 + (idx >> 5);
    const int rem  = idx & 31;
    const int n0   = (rem >> 1) * 64;
    const int half = rem & 1;
    const int mb0  = half * (M_ / 2);
    const int b    = bh >> 4;
    const int h    = bh & 15;

    float* Op = half ? O1 : O0;
    float* rp = half ? rs1 : rs0;

    // mask dtype sniff (per-wave ballot; no barrier needed)
    unsigned am = ((const unsigned*)pmask)[lane] & 0xFFFFFF00u;
    const int mi = (__ballot(am != 0) == 0ull) ? 1 : 0;

    half8 qf[2];
    {
        const _Float16* qp = qw + ((size_t)(b * N_ + n0 + w * 16 + l16) * C_) + h * 64 + quad * 8;
        qf[0] = *(const half8*)qp;
        qf[1] = *(const half8*)(qp + 32);
    }

    f32x4 accO[4];
    float rs[4];
    {
        f32x4 z = {0.f, 0.f, 0.f, 0.f};
        for (int i = 0; i < 4; i++) accO[i] = z;
    }
    #pragma unroll
    for (int r = 0; r < 4; r++) rs[r] = 0.f;

    const _Float16* kbase = kw + (size_t)bh * (M_ * D_);
    const _Float16* vbase = vw + (size_t)bh * (D_ * M_);
    const float*    arow  = alibi + (size_t)bh * ((size_t)N_ * M_) + (size_t)n0 * M_;
    const unsigned char* pm8  = (const unsigned char*)pmask;
    const int*           pm32 = (const int*)pmask;

    // Stage step st's alibi (cols mb0+st*64..+63) for all 64 block rows into
    // Al[st&1]. Per wave: 4 DMA x (64 lanes x 16B). Source pre-swizzled so
    // LDS phys 16B-unit u holds logical unit u ^ 2*((row>>2)&3).
    auto stage = [&](int st) {
        #pragma unroll
        for (int c = 0; c < 4; c++) {
            int rbase = w * 16 + c * 4;                  // wave-uniform
            int rr    = rbase + (lane >> 4);             // lane's source row
            int uu    = (lane & 15) ^ (2 * ((w * 4 + c) & 3));
            const float* src = arow + (size_t)rr * M_ + mb0 + st * 64 + uu * 4;
            gload16f(src, &Al[st & 1][rbase][0]);        // + lane*16B by HW
        }
    };

    stage(0);

    for (int st = 0; st < M_ / 128; st++) {              // 16 steps of 64 cols
        const int m0 = mb0 + st * 64;

        // --- K fragment loads (8) + mask (4) ---
        half8 kf[4][2];
        #pragma unroll
        for (int j = 0; j < 4; j++) {
            const _Float16* kp = kbase + (size_t)(m0 + j * 16 + l16) * D_ + quad * 8;
            kf[j][0] = *(const half8*)kp;
            kf[j][1] = *(const half8*)(kp + 32);
        }
        int mk[4];
        #pragma unroll
        for (int j = 0; j < 4; j++) {
            int mcol = m0 + j * 16 + l16;
            mk[j] = mi ? pm32[b * M_ + mcol] : (int)pm8[b * M_ + mcol];
        }

        // --- QK^T (kf wait drains step-(t-1) alibi DMA before Al reads) ---
        f32x4 s[4];
        {
            f32x4 z = {0.f, 0.f, 0.f, 0.f};
            #pragma unroll
            for (int j = 0; j < 4; j++) s[j] = z;
        }
        #pragma unroll
        for (int j = 0; j < 4; j++) {
            s[j] = __builtin_amdgcn_mfma_f32_16x16x32_f16(qf[0], kf[j][0], s[j], 0, 0, 0);
            s[j] = __builtin_amdgcn_mfma_f32_16x16x32_f16(qf[1], kf[j][1], s[j], 0, 0, 0);
        }

        // --- V fragment loads (8); softmax below covers their L2 latency ---
        half8 vf[2][4];
        #pragma unroll
        for (int kk = 0; kk < 2; kk++)
            #pragma unroll
            for (int dt = 0; dt < 4; dt++)
                vf[kk][dt] = *(const half8*)(vbase + (size_t)(dt * 16 + l16) * M_
                                             + m0 + kk * 32 + quad * 8);

        // --- softmax: alibi from LDS (swizzled), P -> Ps (XOR-swizzled) ---
        #pragma unroll
        for (int j = 0; j < 4; j++) {
            int pu = (j * 4 + (l16 >> 2)) ^ (2 * quad);  // Al phys 16B unit
            int pc = pu * 4 + (l16 & 3);                 // Al phys dword col
            int pd = (j * 8 + (l16 >> 1)) ^ (quad << 3); // Ps phys dword
            int pi = pd * 2 + (l16 & 1);                 // Ps phys fp16 idx
            #pragma unroll
            for (int r = 0; r < 4; r++) {
                float alv = Al[st & 1][w * 16 + quad * 4 + r][pc];
                float sv = fminf(s[j][r] + alv, 11.0f);
                float p  = exp2f(sv * 1.44269504f);
                p = mk[j] ? 0.f : p;
                rs[r] += p;
                Ps[w][quad * 4 + r][pi] = (_Float16)p;
            }
        }

        // --- stage next step's alibi (after this step's Al reads) ---
        __builtin_amdgcn_sched_barrier(0);
        if (st + 1 < M_ / 128) stage(st + 1);
        __builtin_amdgcn_sched_barrier(0);

        // --- O += P V (vf wait keeps the stage DMAs in flight) ---
        #pragma unroll
        for (int kk = 0; kk < 2; kk++) {
            half8 pf = *(const half8*)&Ps[w][l16][(((kk * 16 + quad * 4) ^ ((l16 >> 2) << 3)) * 2)];
            #pragma unroll
            for (int dt = 0; dt < 4; dt++)
                accO[dt] = __builtin_amdgcn_mfma_f32_16x16x32_f16(pf, vf[kk][dt], accO[dt], 0, 0, 0);
        }
    }

    // partial row-sum reduction over the 16 m-col lanes
    #pragma unroll
    for (int off = 1; off < 16; off <<= 1)
        #pragma unroll
        for (int r = 0; r < 4; r++) rs[r] += __shfl_xor(rs[r], off, 64);

    // write unnormalized fp32 partial O + partial row sums
    #pragma unroll
    for (int dt = 0; dt < 4; dt++)
        #pragma unroll
        for (int r = 0; r < 4; r++) {
            int n = n0 + w * 16 + quad * 4 + r;
            Op[(size_t)(b * N_ + n) * C_ + h * 64 + dt * 16 + l16] = accO[dt][r];
        }
    if (l16 == 0) {
        #pragma unroll
        for (int r = 0; r < 4; r++) {
            int n = n0 + w * 16 + quad * 4 + r;
            rp[(size_t)(b * N_ + n) * H_ + h] = rs[r];
        }
    }
}

// ---------------------------------------------------------------------------
// Combine: x = (O0 + O1) * 1/(rs0 + rs1), fp32 -> fp16.  20 MB ~ 3.5 us.
// ---------------------------------------------------------------------------
__global__ __launch_bounds__(256)
void combine(const float* __restrict__ O0, const float* __restrict__ O1,
             const float* __restrict__ rs0, const float* __restrict__ rs1,
             _Float16* __restrict__ x)
{
    int i = blockIdx.x * 256 + threadIdx.x;          // one float4 per thread
    if (i >= B_ * N_ * C_ / 4) return;
    int row = i / (C_ / 4);
    int c4  = (i & (C_ / 4 - 1)) * 4;
    int h   = c4 >> 6;
    float inv = 1.0f / (rs0[row * H_ + h] + rs1[row * H_ + h]);
    float4 a = ((const float4*)O0)[i];
    float4 bb = ((const float4*)O1)[i];
    union { _Float16 hh[4]; unsigned long long u; } pk;
    pk.hh[0] = (_Float16)((a.x + bb.x) * inv);
    pk.hh[1] = (_Float16)((a.y + bb.y) * inv);
    pk.hh[2] = (_Float16)((a.z + bb.z) * inv);
    pk.hh[3] = (_Float16)((a.w + bb.w) * inv);
    ((unsigned long long*)x)[i] = pk.u;
}

// ---------------------------------------------------------------------------
extern "C" void kernel_launch(void* const* d_in, const int* in_sizes, int n_in,
                              void* d_out, int out_size, void* d_ws, size_t ws_size,
                              hipStream_t stream)
{
    const float* q     = (const float*)d_in[0];
    const float* kv    = (const float*)d_in[1];
    const float* alibi = (const float*)d_in[2];
    const void*  pmask = d_in[3];
    const float* Wq    = (const float*)d_in[4];
    const float* Wkv   = (const float*)d_in[5];
    const float* Wproj = (const float*)d_in[6];
    const float* bproj = (const float*)d_in[7];
    float* out = (float*)d_out;

    const size_t MB = 1u << 20;
    char* ws = (char*)d_ws;
    _Float16* qh     = (_Float16*)(ws + 0 * MB);   // [B*N, C]   fp16 (pre-scaled)
    _Float16* kvh    = (_Float16*)(ws + 4 * MB);   // [B*M, KV]  fp16
    _Float16* Wqh    = (_Float16*)(ws + 12 * MB);  // [C, C]
    _Float16* Wkvh   = (_Float16*)(ws + 14 * MB);  // [2C, KV]
    _Float16* Wprojh = (_Float16*)(ws + 18 * MB);  // [C, C]
    _Float16* qp     = (_Float16*)(ws + 20 * MB);  // [B*N, C]   Q proj
    _Float16* k_ws   = (_Float16*)(ws + 24 * MB);  // [B,H,M,D]
    _Float16* v_ws   = (_Float16*)(ws + 33 * MB);  // [B,H,D,M]  (transposed)
    _Float16* x_ws   = (_Float16*)(ws + 42 * MB);  // [B*N, C]   attn out (4 MB)
    float*    O0     = (float*)   (ws + 46 * MB);  // [B*N, C]   fp32 partial (8 MB)
    float*    O1     = (float*)   (ws + 54 * MB);  // [B*N, C]   fp32 partial (8 MB)
    float*    rs0    = (float*)   (ws + 62 * MB);  // [B*N, H]   fp32 (128 KB)
    float*    rs1    = (float*)   (ws + 63 * MB);  // [B*N, H]   fp32 (128 KB)

    cvt_all<<<(NTOT4 + 255) / 256, 256, 0, stream>>>(
        q, kv, Wq, Wkv, Wproj, qh, kvh, Wqh, Wkvh, Wprojh);

    qkv_gemm<<<640, 256, 0, stream>>>(qh, Wqh, qp, kvh, Wkvh, k_ws, v_ws);

    flash_attn<<<1024, 256, 0, stream>>>(
        qp, k_ws, v_ws, alibi, pmask, O0, O1, rs0, rs1);

    combine<<<(B_ * N_ * C_ / 4 + 255) / 256, 256, 0, stream>>>(
        O0, O1, rs0, rs1, x_ws);

    outproj<<<dim3(C_ / 64, (B_ * N_) / 64), 256, 0, stream>>>(
        x_ws, Wprojh, out, bproj);
}